// Round 2
// baseline (1328.382 us; speedup 1.0000x reference)
//
#include <hip/hip_runtime.h>
#include <hip/hip_bf16.h>

#define BATCH 64
#define SEQ   512
#define INPD  128
#define HID   256
#define G4    1024   // 4*HID

// 256 blocks x 512 threads. Block = (batch b, part p): owns hidden units
// [64p, 64p+64) => 256 gate columns {g*256 + 64p + jj : g in 0..3, jj in 0..63}.
// thread tid: c = tid & 255 (block-local gate column), kh = tid >> 8 (k-half).
// Weights held ENTIRELY in VGPRs: w_h[128] = Wh[kh*128+i][gcol], w_i[64] = Wi[kh*64+i][gcol].
// Cross-block h exchange via step-tagged 64-bit relaxed device-scope atomics
// (tag<<32 | f32bits), double-buffered by step parity. No fences needed:
// the tag and value travel in one atomic word.

__global__ __launch_bounds__(512, 2)
void ChaoticLSTM_kernel(const float* __restrict__ x,  const float* __restrict__ Wi,
                        const float* __restrict__ Wh, const float* __restrict__ Bb,
                        float* __restrict__ out, unsigned long long* __restrict__ exch)
{
    const int bid  = blockIdx.x;
    const int xcd  = bid & 7;
    const int slot = bid >> 3;
    const int b    = xcd * 8 + (slot >> 2);   // batch element
    const int part = slot & 3;                // which 64-unit chunk of H
    const int tid  = threadIdx.x;
    const int c    = tid & 255;               // block-local gate column
    const int kh   = tid >> 8;                // 0 or 1: k-half
    const int g    = c >> 6;                  // 0:i 1:f 2:g 3:o
    const int jj   = c & 63;
    const int gcol = g * 256 + part * 64 + jj;   // global gate column in [0,1024)

    __shared__ __align__(16) float h_lds[HID];
    __shared__ __align__(16) float x_lds[INPD];
    __shared__ float ps[2][256];
    __shared__ float act[256];

    // ---- load weight slices into registers (fully static indexing) ----
    float w_h[128];
#pragma unroll
    for (int i = 0; i < 128; ++i) w_h[i] = Wh[(size_t)(kh * 128 + i) * G4 + gcol];
    float w_i[64];
#pragma unroll
    for (int i = 0; i < 64; ++i)  w_i[i] = Wi[(size_t)(kh * 64 + i) * G4 + gcol];

    const float Breg = Bb[gcol];

    unsigned long long* __restrict__ exb = exch + (size_t)b * 512;

    // ---- init ----
    float cs = 0.f;                         // cell state (threads tid<64 only)
    if (tid < 256) h_lds[tid] = 0.f;
    if (tid >= 256 && tid < 384)
        x_lds[tid - 256] = x[(size_t)(b * SEQ) * INPD + (tid - 256)];
    if (tid < 64) {                         // insurance: clear my exchange slots
        int j = part * 64 + jj;
        __hip_atomic_store(&exb[j],       0ull, __ATOMIC_RELAXED, __HIP_MEMORY_SCOPE_AGENT);
        __hip_atomic_store(&exb[256 + j], 0ull, __ATOMIC_RELAXED, __HIP_MEMORY_SCOPE_AGENT);
    }
    __syncthreads();

    float xnext = 0.f;
    for (int st = 0; st < SEQ; ++st) {
        // ---- Phase A: partial matvec (h @ Wh-slice + x @ Wi-slice), weights in regs ----
        float a0 = 0.f, a1 = 0.f, a2 = 0.f, a3 = 0.f;
        const float4* h4 = (const float4*)(h_lds + kh * 128);
#pragma unroll
        for (int i = 0; i < 32; ++i) {
            float4 hv = h4[i];                       // uniform LDS broadcast
            a0 = fmaf(hv.x, w_h[4*i+0], a0);
            a1 = fmaf(hv.y, w_h[4*i+1], a1);
            a2 = fmaf(hv.z, w_h[4*i+2], a2);
            a3 = fmaf(hv.w, w_h[4*i+3], a3);
        }
        const float4* x4 = (const float4*)(x_lds + kh * 64);
#pragma unroll
        for (int i = 0; i < 16; ++i) {
            float4 xv = x4[i];
            a0 = fmaf(xv.x, w_i[4*i+0], a0);
            a1 = fmaf(xv.y, w_i[4*i+1], a1);
            a2 = fmaf(xv.z, w_i[4*i+2], a2);
            a3 = fmaf(xv.w, w_i[4*i+3], a3);
        }
        ps[kh][c] = (a0 + a1) + (a2 + a3);
        __syncthreads();

        // ---- Phase B: gate activations (waves 0-3); x prefetch (wave 4-5) ----
        if (tid < 256) {
            float gs = Breg + ps[0][c] + ps[1][c];
            float a;
            if (g == 2) a = tanhf(gs);
            else        a = 1.f / (1.f + expf(-gs));
            act[c] = a;
        } else if (tid < 384 && st + 1 < SEQ) {
            xnext = x[(size_t)(b * SEQ + st + 1) * INPD + (tid - 256)];
        }
        __syncthreads();

        // ---- Phase C: state update + exchange ----
        const unsigned long long tag = (unsigned long long)(st + 1);
        unsigned long long* slotp = exb + (st & 1) * 256;
        if (tid < 64) {
            float iv = act[jj], fv = act[64 + jj], gv = act[128 + jj], ov = act[192 + jj];
            cs = fv * cs + iv * gv;
            float hn = ov * tanhf(cs);
            int j = part * 64 + jj;
            h_lds[j] = hn;
            out[(size_t)(b * SEQ + st) * HID + j] = hn;
            unsigned long long w = (tag << 32) | (unsigned long long)__float_as_uint(hn);
            __hip_atomic_store(&slotp[j], w, __ATOMIC_RELAXED, __HIP_MEMORY_SCOPE_AGENT);
        } else if (tid < 256) {
            int q   = tid >> 6;                 // 1..3
            int pp  = (part + q) & 3;           // partner part
            int idx = pp * 64 + jj;
            unsigned long long v;
            do {
                v = __hip_atomic_load(&slotp[idx], __ATOMIC_RELAXED, __HIP_MEMORY_SCOPE_AGENT);
            } while ((unsigned)(v >> 32) != (unsigned)tag);
            h_lds[idx] = __uint_as_float((unsigned)v);
        } else if (tid < 384) {
            x_lds[tid - 256] = xnext;           // stale write at st=511 is never read
        }
        __syncthreads();
    }

    // ---- epilogue: ht, ct ----
    if (tid < 64) {
        int j = part * 64 + jj;
        size_t base = (size_t)BATCH * SEQ * HID;
        out[base + (size_t)b * HID + j] = h_lds[j];
        out[base + (size_t)BATCH * HID + (size_t)b * HID + j] = cs;
    }
}

extern "C" void kernel_launch(void* const* d_in, const int* in_sizes, int n_in,
                              void* d_out, int out_size, void* d_ws, size_t ws_size,
                              hipStream_t stream) {
    const float* x  = (const float*)d_in[0];
    const float* Wi = (const float*)d_in[1];
    const float* Wh = (const float*)d_in[2];
    const float* B  = (const float*)d_in[3];
    float* out = (float*)d_out;
    unsigned long long* exch = (unsigned long long*)d_ws;   // 64*512*8 = 256 KB

    ChaoticLSTM_kernel<<<dim3(256), dim3(512), 0, stream>>>(x, Wi, Wh, B, out, exch);
}

// Round 3
// 919.633 us; speedup vs baseline: 1.4445x; 1.4445x over previous
//
#include <hip/hip_runtime.h>
#include <hip/hip_bf16.h>

#define BATCH 64
#define SEQ   512
#define INPD  128
#define HID   256
#define G4    1024   // 4*HID
#define PSS   272    // padded ps row stride in floats (16*272*4B, 2-way banks max)

// 256 blocks x 512 threads. Block = (batch b, part p): owns 64 hidden units,
// 256 gate columns. Thread layout: CG = tid>>4 (32 column-groups of 8 cols),
// S = tid&15 (16 k-slices: 16 h-rows + 8 x-rows each).
// Weights in registers: 192 floats/thread (wh[16][8], wi[8][8]).
// Per step: hFMA (broadcast LDS reads, 4 b128/thread) -> ps partials ->
// cross-slice reduce + activation (256 threads) -> update/exchange.
// x-projection for step st+1 computed during the exchange RTT window from
// global-loaded x regs (issued at step start).
// Cross-block h exchange: step-tagged 64-bit relaxed agent-scope atomics,
// double-buffered by parity (value-carried ordering, no fences).

#define HF(hv, rb) { \
    acc0 = fmaf(hv, wh[(rb)*8+0], acc0); acc1 = fmaf(hv, wh[(rb)*8+1], acc1); \
    acc2 = fmaf(hv, wh[(rb)*8+2], acc2); acc3 = fmaf(hv, wh[(rb)*8+3], acc3); \
    acc4 = fmaf(hv, wh[(rb)*8+4], acc4); acc5 = fmaf(hv, wh[(rb)*8+5], acc5); \
    acc6 = fmaf(hv, wh[(rb)*8+6], acc6); acc7 = fmaf(hv, wh[(rb)*8+7], acc7); }

#define XSET(xv) { \
    acc0 = xv * wi[0]; acc1 = xv * wi[1]; acc2 = xv * wi[2]; acc3 = xv * wi[3]; \
    acc4 = xv * wi[4]; acc5 = xv * wi[5]; acc6 = xv * wi[6]; acc7 = xv * wi[7]; }

#define XF(xv, rb) { \
    acc0 = fmaf(xv, wi[(rb)*8+0], acc0); acc1 = fmaf(xv, wi[(rb)*8+1], acc1); \
    acc2 = fmaf(xv, wi[(rb)*8+2], acc2); acc3 = fmaf(xv, wi[(rb)*8+3], acc3); \
    acc4 = fmaf(xv, wi[(rb)*8+4], acc4); acc5 = fmaf(xv, wi[(rb)*8+5], acc5); \
    acc6 = fmaf(xv, wi[(rb)*8+6], acc6); acc7 = fmaf(xv, wi[(rb)*8+7], acc7); }

#define XPART_ALL { \
    XSET(nx0.x) XF(nx0.y, 1) XF(nx0.z, 2) XF(nx0.w, 3) \
    XF(nx1.x, 4) XF(nx1.y, 5) XF(nx1.z, 6) XF(nx1.w, 7) }

__global__ __launch_bounds__(512, 2)
void ChaoticLSTM_kernel(const float* __restrict__ x,  const float* __restrict__ Wi,
                        const float* __restrict__ Wh, const float* __restrict__ Bb,
                        float* __restrict__ out, unsigned long long* __restrict__ exch)
{
    const int bid  = blockIdx.x;
    const int xcd  = bid & 7;
    const int slotn = bid >> 3;
    const int b    = xcd * 8 + (slotn >> 2);  // batch element
    const int part = slotn & 3;               // 64-unit chunk of H
    const int tid  = threadIdx.x;
    const int CG   = tid >> 4;                // 0..31: column group (8 cols)
    const int S    = tid & 15;                // 0..15: k-slice
    const int g    = CG >> 3;                 // gate of this thread's columns
    const int jj0  = (CG & 7) * 8;
    const int gcol0 = g * 256 + part * 64 + jj0;  // first global gate column

    __shared__ __align__(16) float h_lds[HID];
    __shared__ __align__(16) float ps[16 * PSS];
    __shared__ float act[256];

    // ---- weights into registers (static indexing throughout) ----
    float wh[128];   // [r<16][cc<8] : h-rows S*16..S*16+15
    float wi[64];    // [r<8][cc<8]  : x-rows S*8..S*8+7
#pragma unroll
    for (int r = 0; r < 16; ++r) {
        const float* p = Wh + (size_t)(S * 16 + r) * G4 + gcol0;
        float4 u0 = *(const float4*)p;
        float4 u1 = *(const float4*)(p + 4);
        wh[r*8+0] = u0.x; wh[r*8+1] = u0.y; wh[r*8+2] = u0.z; wh[r*8+3] = u0.w;
        wh[r*8+4] = u1.x; wh[r*8+5] = u1.y; wh[r*8+6] = u1.z; wh[r*8+7] = u1.w;
    }
#pragma unroll
    for (int r = 0; r < 8; ++r) {
        const float* p = Wi + (size_t)(S * 8 + r) * G4 + gcol0;
        float4 u0 = *(const float4*)p;
        float4 u1 = *(const float4*)(p + 4);
        wi[r*8+0] = u0.x; wi[r*8+1] = u0.y; wi[r*8+2] = u0.z; wi[r*8+3] = u0.w;
        wi[r*8+4] = u1.x; wi[r*8+5] = u1.y; wi[r*8+6] = u1.z; wi[r*8+7] = u1.w;
    }
    const float Bred = (tid < 256) ? Bb[(tid >> 6) * 256 + part * 64 + (tid & 63)] : 0.f;

    unsigned long long* __restrict__ exb = exch + (size_t)b * 512;
    const float* __restrict__ xrow = x + (size_t)b * SEQ * INPD + S * 8;

    // ---- init ----
    float cs = 0.f;
    if (tid < 256) h_lds[tid] = 0.f;
    if (tid < 64) {   // insurance: clear own exchange slots (both parities)
        __hip_atomic_store(&exb[part*64 + tid],       0ull, __ATOMIC_RELAXED, __HIP_MEMORY_SCOPE_AGENT);
        __hip_atomic_store(&exb[256 + part*64 + tid], 0ull, __ATOMIC_RELAXED, __HIP_MEMORY_SCOPE_AGENT);
    }

    float acc0, acc1, acc2, acc3, acc4, acc5, acc6, acc7;
    {   // acc = x-part for step 0
        float4 nx0 = *(const float4*)(xrow);
        float4 nx1 = *(const float4*)(xrow + 4);
        XPART_ALL;
    }
    __syncthreads();

    for (int st = 0; st < SEQ; ++st) {
        // issue x loads for step st+1 early (consumed in phase 3)
        const float* xp = xrow + (size_t)((st + 1 < SEQ) ? st + 1 : st) * INPD;
        float4 nx0 = *(const float4*)(xp);
        float4 nx1 = *(const float4*)(xp + 4);

        // ---- Phase 1: h-part of matvec (broadcast LDS reads, 4x b128) ----
        {
            float4 hv;
            hv = *(const float4*)(h_lds + S * 16);
            HF(hv.x, 0)  HF(hv.y, 1)  HF(hv.z, 2)  HF(hv.w, 3)
            hv = *(const float4*)(h_lds + S * 16 + 4);
            HF(hv.x, 4)  HF(hv.y, 5)  HF(hv.z, 6)  HF(hv.w, 7)
            hv = *(const float4*)(h_lds + S * 16 + 8);
            HF(hv.x, 8)  HF(hv.y, 9)  HF(hv.z, 10) HF(hv.w, 11)
            hv = *(const float4*)(h_lds + S * 16 + 12);
            HF(hv.x, 12) HF(hv.y, 13) HF(hv.z, 14) HF(hv.w, 15)
        }
        {   // write 8 partials
            float4 A = make_float4(acc0, acc1, acc2, acc3);
            float4 Bv = make_float4(acc4, acc5, acc6, acc7);
            *(float4*)(ps + S * PSS + CG * 8)     = A;
            *(float4*)(ps + S * PSS + CG * 8 + 4) = Bv;
        }
        __syncthreads();

        // ---- Phase 2: reduce 16 partials + activation (tid<256, 1 col each) ----
        if (tid < 256) {
            const int c = tid;
            float t0 = ps[0*PSS+c]  + ps[1*PSS+c];
            float t1 = ps[2*PSS+c]  + ps[3*PSS+c];
            float t2 = ps[4*PSS+c]  + ps[5*PSS+c];
            float t3 = ps[6*PSS+c]  + ps[7*PSS+c];
            float t4 = ps[8*PSS+c]  + ps[9*PSS+c];
            float t5 = ps[10*PSS+c] + ps[11*PSS+c];
            float t6 = ps[12*PSS+c] + ps[13*PSS+c];
            float t7 = ps[14*PSS+c] + ps[15*PSS+c];
            float gs = Bred + (((t0 + t1) + (t2 + t3)) + ((t4 + t5) + (t6 + t7)));
            float a;
            if ((tid >> 6) == 2) a = tanhf(gs);
            else                 a = 1.f / (1.f + expf(-gs));
            act[c] = a;
        }
        __syncthreads();

        // ---- Phase 3: update + exchange; x-part(st+1) hidden in RTT window ----
        const unsigned tag = (unsigned)(st + 1);
        unsigned long long* slotp = exb + (st & 1) * 256;
        unsigned long long v = 0; int idx = 0;
        if (tid < 64) {
            float iv = act[tid], fv = act[64 + tid], gv = act[128 + tid], ov = act[192 + tid];
            cs = fv * cs + iv * gv;
            float hn = ov * tanhf(cs);
            int j = part * 64 + tid;
            unsigned long long w = ((unsigned long long)tag << 32)
                                 | (unsigned long long)__float_as_uint(hn);
            __hip_atomic_store(&slotp[j], w, __ATOMIC_RELAXED, __HIP_MEMORY_SCOPE_AGENT); // first: partners wait on this
            h_lds[j] = hn;
            out[(size_t)(b * SEQ + st) * HID + j] = hn;
        } else if (tid < 256) {
            int q  = tid >> 6;                  // 1..3
            int pp = (part + q) & 3;
            idx = pp * 64 + (tid & 63);
            v = __hip_atomic_load(&slotp[idx], __ATOMIC_RELAXED, __HIP_MEMORY_SCOPE_AGENT);
        }
        XPART_ALL;                              // all threads: x-part for st+1
        if (tid >= 64 && tid < 256) {
            while ((unsigned)(v >> 32) != tag)
                v = __hip_atomic_load(&slotp[idx], __ATOMIC_RELAXED, __HIP_MEMORY_SCOPE_AGENT);
            h_lds[idx] = __uint_as_float((unsigned)v);
        }
        __syncthreads();
    }

    // ---- epilogue: ht, ct ----
    if (tid < 64) {
        int j = part * 64 + tid;
        size_t base = (size_t)BATCH * SEQ * HID;
        out[base + (size_t)b * HID + j] = h_lds[j];
        out[base + (size_t)BATCH * HID + (size_t)b * HID + j] = cs;
    }
}

extern "C" void kernel_launch(void* const* d_in, const int* in_sizes, int n_in,
                              void* d_out, int out_size, void* d_ws, size_t ws_size,
                              hipStream_t stream) {
    const float* x  = (const float*)d_in[0];
    const float* Wi = (const float*)d_in[1];
    const float* Wh = (const float*)d_in[2];
    const float* B  = (const float*)d_in[3];
    float* out = (float*)d_out;
    unsigned long long* exch = (unsigned long long*)d_ws;   // 64*512*8 = 256 KB

    ChaoticLSTM_kernel<<<dim3(256), dim3(512), 0, stream>>>(x, Wi, Wh, B, out, exch);
}